// Round 9
// baseline (451.005 us; speedup 1.0000x reference)
//
#include <hip/hip_runtime.h>

#define B_ 256
#define T_ 512
#define F_ 64
#define U_ 128

typedef _Float16 h2v __attribute__((ext_vector_type(2)));
union U32H2 { unsigned u; h2v h; };

__device__ __forceinline__ float fdot2(unsigned a, unsigned b, float c) {
  U32H2 x, y; x.u = a; y.u = b;
  return __builtin_amdgcn_fdot2(x.h, y.h, c, false);
}
__device__ __forceinline__ unsigned packh2(float a, float b) {
  U32H2 r; r.h[0] = (_Float16)a; r.h[1] = (_Float16)b; return r.u;
}
// exchange value within lane pair (quad_perm [1,0,3,2]); returns partner's v
__device__ __forceinline__ float pairswap(float v) {
  return __int_as_float(
      __builtin_amdgcn_update_dpp(0, __float_as_int(v), 0xB1, 0xF, 0xF, true));
}
__device__ __forceinline__ float pairsum(float v) {
  return v + pairswap(v);
}
__device__ __forceinline__ float fast_sig(float x) {
  return __builtin_amdgcn_rcpf(1.0f + __expf(-x));
}
__device__ __forceinline__ float fast_tanh(float x) {
  return fmaf(-2.0f, __builtin_amdgcn_rcpf(1.0f + __expf(2.0f * x)), 1.0f);
}

#define D4(acc, Hv, Wr, o)                                        \
  acc = fdot2(Hv.x, Wr[(o)], acc);                                \
  acc = fdot2(Hv.y, Wr[(o) + 1], acc);                            \
  acc = fdot2(Hv.z, Wr[(o) + 2], acc);                            \
  acc = fdot2(Hv.w, Wr[(o) + 3], acc);

__global__ __launch_bounds__(256, 1)
__attribute__((amdgpu_waves_per_eu(1, 1)))
void grud_kernel(
    const float* __restrict__ x, const float* __restrict__ m,
    const float* __restrict__ delta_t,
    const float* __restrict__ Wz_, const float* __restrict__ Uz, const float* __restrict__ bz,
    const float* __restrict__ Wr_, const float* __restrict__ Ur, const float* __restrict__ br,
    const float* __restrict__ Wh_, const float* __restrict__ Uh, const float* __restrict__ bh,
    const float* __restrict__ gxd, const float* __restrict__ ghd,
    const float* __restrict__ mi,
    float* __restrict__ out)
{
  const int tid = threadIdx.x;
  const int b   = blockIdx.x;
  const int c   = tid >> 1;    // owned output column (2 lanes per column)
  const int p   = tid & 1;     // role/parity: p0 -> z-gate, p1 -> r-gate
  const bool p0 = (p == 0);

  __shared__ float  s_ax[3 * 32 * U_];       // 48KB: az|ar|ah (+bias) per chunk
  __shared__ __align__(16) ushort s_hist16[32 * U_]; // 8KB; first 4KB reused as x16
  __shared__ float  s_dt[40];
  __shared__ float  s_gxf[F_], s_mi[F_];
  __shared__ __align__(16) ushort s_hd16[U_];
  __shared__ __align__(16) ushort s_rh16[U_];
  ushort* const s_x16 = s_hist16;            // [32][64] fp16 (staging only)

  // ---- weights into registers ----
  unsigned uf[64];                 // FULL column: Uz (p0) or Ur (p1)
  unsigned uh[32];                 // Uh, k-half [64p, 64p+64)
  unsigned wz[16], wr[16], wh[16]; // W f-half [32p, 32p+32) (staging only)
  {
    const float* Ucol = p0 ? Uz : Ur;
#pragma unroll
    for (int j = 0; j < 64; ++j)
      uf[j] = packh2(Ucol[(2 * j) * U_ + c], Ucol[(2 * j + 1) * U_ + c]);
#pragma unroll
    for (int j = 0; j < 32; ++j) {
      const int k0 = 64 * p + 2 * j;
      uh[j] = packh2(Uh[k0 * U_ + c], Uh[(k0 + 1) * U_ + c]);
    }
#pragma unroll
    for (int j = 0; j < 16; ++j) {
      const int f0 = 32 * p + 2 * j;
      wz[j] = packh2(Wz_[f0 * U_ + c], Wz_[(f0 + 1) * U_ + c]);
      wr[j] = packh2(Wr_[f0 * U_ + c], Wr_[(f0 + 1) * U_ + c]);
      wh[j] = packh2(Wh_[f0 * U_ + c], Wh_[(f0 + 1) * U_ + c]);
    }
  }
  // per-role scalars
  const float bz_c = p0 ? bz[c] : 0.0f;
  const float bh_c = p0 ? bh[c] : 0.0f;
  const float br_c = p0 ? 0.0f  : br[c];
  const float negg = p0 ? 0.0f  : -fmaxf(ghd[c], 0.0f);

  if (tid < F_) { s_gxf[tid] = -fmaxf(gxd[tid], 0.0f); s_mi[tid] = mi[tid]; }
  if (tid < 64) ((unsigned*)s_hd16)[tid] = 0u;   // h0 = 0
  __syncthreads();

  float hd_own = 0.0f;   // h_dec for column c (both lanes)
  float zreg   = 0.0f;   // z (valid on p0)

  for (int t0 = 0; t0 < T_; t0 += 32) {
    // ---- flush previous chunk's hist (fp16 -> fp32, coalesced) ----
    if (t0 > 0) {
      const uint4 ha = *(const uint4*)(s_hist16 + 16 * tid);
      const uint4 hb = *(const uint4*)(s_hist16 + 16 * tid + 8);
      float* ob = out + (size_t)(b * T_ + (t0 - 32)) * U_ + 16 * tid;
      const unsigned wa[8] = {ha.x, ha.y, ha.z, ha.w, hb.x, hb.y, hb.z, hb.w};
#pragma unroll
      for (int i = 0; i < 8; ++i) {
        U32H2 u; u.u = wa[i];
        ob[2 * i]     = (float)u.h[0];
        ob[2 * i + 1] = (float)u.h[1];
      }
      __syncthreads();   // flush reads done before x16 overwrite
    }

    // ---- stage dt + decayed x (fp16) ----
    if (tid < 33) {
      const int t = t0 + tid;
      s_dt[tid] = (t < T_) ? delta_t[b * T_ + t] : 0.0f;
    }
#pragma unroll
    for (int i = 0; i < 2; ++i) {
      const int e4 = tid + 256 * i;            // 0..511 quad-groups of [32][64]
      const int t = e4 >> 4, f0 = (e4 & 15) << 2;
      const float dtv = delta_t[b * T_ + t0 + t];
      const float4 xv  = *(const float4*)(x + (size_t)(b * T_ + t0 + t) * F_ + f0);
      const float4 mv  = *(const float4*)(m + (size_t)(b * T_ + t0 + t) * F_ + f0);
      const float4 gv  = *(const float4*)(s_gxf + f0);
      const float4 miv = *(const float4*)(s_mi + f0);
      float gx, d0, d1, d2, d3;
      gx = __expf(gv.x * dtv);
      d0 = fmaf(mv.x, xv.x, (1.0f - mv.x) * (gx * xv.x + (1.0f - gx) * miv.x));
      gx = __expf(gv.y * dtv);
      d1 = fmaf(mv.y, xv.y, (1.0f - mv.y) * (gx * xv.y + (1.0f - gx) * miv.y));
      gx = __expf(gv.z * dtv);
      d2 = fmaf(mv.z, xv.z, (1.0f - mv.z) * (gx * xv.z + (1.0f - gx) * miv.z));
      gx = __expf(gv.w * dtv);
      d3 = fmaf(mv.w, xv.w, (1.0f - mv.w) * (gx * xv.w + (1.0f - gx) * miv.w));
      uint2 px; px.x = packh2(d0, d1); px.y = packh2(d2, d3);
      *(uint2*)(s_x16 + 4 * e4) = px;
    }
    __syncthreads();

    // ---- precompute x-projections for the whole chunk (bulk) ----
#pragma unroll 2
    for (int t = 0; t < 32; ++t) {
      const uint4* xp = (const uint4*)(s_x16 + t * F_ + 32 * p);
      float a0 = 0.f, a1 = 0.f, a2 = 0.f;
#pragma unroll
      for (int q = 0; q < 4; ++q) {
        const uint4 Xv = xp[q];
        D4(a0, Xv, wz, 4 * q) D4(a1, Xv, wr, 4 * q) D4(a2, Xv, wh, 4 * q)
      }
      a0 = pairsum(a0); a1 = pairsum(a1); a2 = pairsum(a2);
      if (p0) {
        s_ax[t * U_ + c]            = a0 + bz_c;   // az
        s_ax[2 * 4096 + t * U_ + c] = a2 + bh_c;   // ah
      } else {
        s_ax[4096 + t * U_ + c]     = a1 + br_c;   // ar
      }
    }
    __syncthreads();

    // ======== 32 recurrent steps ========
#pragma unroll 2
    for (int tc = 0; tc < 32; ++tc) {
      // ---- window B: own gate (z on p0, r on p1), full 128-k dot ----
      const float axg = s_ax[p * 4096 + tc * U_ + c];
      const uint4* hp = (const uint4*)s_hd16;
      float a0 = 0.f, a1 = 0.f, a2 = 0.f, a3 = 0.f;
#pragma unroll
      for (int q = 0; q < 4; ++q) {
        const uint4 Ha = hp[4 * q + 0], Hb = hp[4 * q + 1];
        const uint4 Hc = hp[4 * q + 2], Hd = hp[4 * q + 3];
        D4(a0, Ha, uf, 16 * q)      D4(a1, Hb, uf, 16 * q + 4)
        D4(a2, Hc, uf, 16 * q + 8)  D4(a3, Hd, uf, 16 * q + 12)
      }
      const float g = fast_sig(((a0 + a1) + (a2 + a3)) + axg);
      if (p0) zreg = g;
      else    ((_Float16*)s_rh16)[c] = (_Float16)(g * hd_own);
      __syncthreads();

      // ---- window C: candidate + update ----
      const float axh = s_ax[2 * 4096 + tc * U_ + c];
      float gh = 0.0f;
      if (!p0) gh = __expf(negg * s_dt[tc + 1]);   // off-path on p1
      const uint4* rp = (const uint4*)(s_rh16 + 64 * p);
      float h0 = 0.f, h1 = 0.f;
#pragma unroll
      for (int q = 0; q < 4; ++q) {
        const uint4 Ra = rp[q], Rb = rp[q + 4];
        D4(h0, Ra, uh, 4 * q)  D4(h1, Rb, uh, 4 * q + 16)
      }
      const float ah = pairsum(h0 + h1) + axh;
      const float hh = fast_tanh(ah);
      const float gh_sw = pairswap(gh);            // p0 <- p1's gh
      const float hn = fmaf(zreg, hh - hd_own, hd_own);  // valid on p0
      if (p0) ((_Float16*)s_hist16)[tc * U_ + c] = (_Float16)hn;
      const float hdn = gh_sw * hn;                // valid on p0
      const float hdn_sw = pairswap(hdn);          // p1 <- p0's hdn
      hd_own = p0 ? hdn : hdn_sw;
      if (p0) ((_Float16*)s_hd16)[c] = (_Float16)hd_own;
      __syncthreads();
    }
  }

  // ---- flush last chunk ----
  {
    const uint4 ha = *(const uint4*)(s_hist16 + 16 * tid);
    const uint4 hb = *(const uint4*)(s_hist16 + 16 * tid + 8);
    float* ob = out + (size_t)(b * T_ + (T_ - 32)) * U_ + 16 * tid;
    const unsigned wa[8] = {ha.x, ha.y, ha.z, ha.w, hb.x, hb.y, hb.z, hb.w};
#pragma unroll
    for (int i = 0; i < 8; ++i) {
      U32H2 u; u.u = wa[i];
      ob[2 * i]     = (float)u.h[0];
      ob[2 * i + 1] = (float)u.h[1];
    }
  }
}

extern "C" void kernel_launch(void* const* d_in, const int* in_sizes, int n_in,
                              void* d_out, int out_size, void* d_ws, size_t ws_size,
                              hipStream_t stream) {
  const float* x   = (const float*)d_in[0];
  const float* m   = (const float*)d_in[1];
  const float* dt  = (const float*)d_in[2];
  const float* Wz  = (const float*)d_in[3];
  const float* Uz  = (const float*)d_in[4];
  const float* bz  = (const float*)d_in[5];
  const float* Wr  = (const float*)d_in[6];
  const float* Ur  = (const float*)d_in[7];
  const float* br  = (const float*)d_in[8];
  const float* Wh  = (const float*)d_in[9];
  const float* Uh  = (const float*)d_in[10];
  const float* bh  = (const float*)d_in[11];
  const float* gxd = (const float*)d_in[12];
  const float* ghd = (const float*)d_in[13];
  const float* mi  = (const float*)d_in[14];

  grud_kernel<<<dim3(B_), dim3(256), 0, stream>>>(
      x, m, dt, Wz, Uz, bz, Wr, Ur, br, Wh, Uh, bh, gxd, ghd, mi, (float*)d_out);
}